// Round 1
// baseline (572.879 us; speedup 1.0000x reference)
//
#include <hip/hip_runtime.h>
#include <hip/hip_fp16.h>
#include <math.h>

#define N_NODES 100000
#define N_EDGES 1600000
#define F_IN 15
#define NB_NODES 391   // ceil(N_NODES/256)
#define MASK40 ((1ull << 40) - 1)

typedef _Float16 half8 __attribute__((ext_vector_type(8)));
typedef float f32x4 __attribute__((ext_vector_type(4)));

// Physical XCD id (0..7 on MI355X). hwreg id 20 = HW_REG_XCC_ID, offset 0,
// size 4 bits -> imm = 20 | (0<<6) | ((4-1)<<11).
__device__ __forceinline__ int xcc_id() {
    return (int)(__builtin_amdgcn_s_getreg(20 | (3 << 11)) & 7);
}

// ---------------- prelude ----------------

__global__ void k_initp(unsigned long long* __restrict__ packed8) {
    int i = blockIdx.x * blockDim.x + threadIdx.x;
    if (i < 8 * N_NODES) packed8[i] = 0ull;
}

// 8-way XCD-local replicated histogram: copy = PHYSICAL XCD id, and the
// atomic is workgroup-scope, so the RMW executes in the local XCD's L2
// (L2 is the intra-XCD coherence point; no cross-XCD aliasing since each
// copy is only ever touched from its own XCD). Avoids the agent-scope
// sc1 write-through to the memory side that made this kernel 72 us.
// One packed 64-bit atomic per edge: count in [40..], weight-sum 32.8 fx
// below. Returned old count = within-copy CSR ordinal; copy packed into
// ord bits [28..30] since it is no longer derivable from the edge index.
__global__ void k_cnt(const int* __restrict__ dst, const float* __restrict__ w,
                      unsigned long long* __restrict__ packed8, int* __restrict__ ord) {
    int i = blockIdx.x * blockDim.x + threadIdx.x;
    if (i >= N_EDGES) return;
    int copy = xcc_id();
    int d = dst[i];
    unsigned long long contrib =
        (1ull << 40) + (unsigned long long)((double)w[i] * 4294967296.0);
    unsigned long long old = __hip_atomic_fetch_add(
        &packed8[(size_t)copy * N_NODES + d], contrib,
        __ATOMIC_RELAXED, __HIP_MEMORY_SCOPE_WORKGROUP);
    ord[i] = (int)(old >> 40) | (copy << 28);
}

// per-block sum of (8-copy) counts -> bsum; fused dinv = rsqrt(1 + sum_w)
__global__ void k_part(const unsigned long long* __restrict__ packed8,
                       int* __restrict__ bsum, float* __restrict__ dinv) {
    __shared__ int red[256];
    int t = threadIdx.x;
    int i = blockIdx.x * 256 + t;
    int c = 0;
    if (i < N_NODES) {
        unsigned long long wsum = 0;
#pragma unroll
        for (int cp = 0; cp < 8; cp++) {
            unsigned long long p = packed8[(size_t)cp * N_NODES + i];
            c += (int)(p >> 40);
            wsum += (p & MASK40);
        }
        float deg = 1.0f + (float)((double)wsum * 0x1p-32);
        dinv[i] = rsqrtf(deg);
    }
    red[t] = c;
    __syncthreads();
    for (int off = 128; off > 0; off >>= 1) {
        if (t < off) red[t] += red[t + off];
        __syncthreads();
    }
    if (t == 0) bsum[blockIdx.x] = red[0];
}

__global__ __launch_bounds__(512) void k_scanb(int* __restrict__ bsum,
                                               int* __restrict__ rowptr) {
    __shared__ int sc[512];
    int t = threadIdx.x;
    int v = (t < NB_NODES) ? bsum[t] : 0;
    sc[t] = v;
    __syncthreads();
    for (int off = 1; off < 512; off <<= 1) {
        int u = (t >= off) ? sc[t - off] : 0;
        __syncthreads();
        sc[t] += u;
        __syncthreads();
    }
    if (t < NB_NODES) bsum[t] = sc[t] - v;
    if (t == 0) rowptr[N_NODES] = N_EDGES;
}

// in-block exclusive scan of total counts -> rowptr; also per-copy bases rbase[cp][n]
__global__ void k_fillptr(const unsigned long long* __restrict__ packed8,
                          const int* __restrict__ bsum, int* __restrict__ rowptr,
                          int* __restrict__ rbase) {
    __shared__ int sc[256];
    int t = threadIdx.x;
    int i = blockIdx.x * 256 + t;
    int cnts[8];
    int v = 0;
    if (i < N_NODES) {
#pragma unroll
        for (int cp = 0; cp < 8; cp++) {
            cnts[cp] = (int)(packed8[(size_t)cp * N_NODES + i] >> 40);
            v += cnts[cp];
        }
    }
    sc[t] = v;
    __syncthreads();
    for (int off = 1; off < 256; off <<= 1) {
        int u = (t >= off) ? sc[t - off] : 0;
        __syncthreads();
        sc[t] += u;
        __syncthreads();
    }
    if (i < N_NODES) {
        int run = bsum[blockIdx.x] + sc[t] - v;  // exclusive prefix = rowptr
        rowptr[i] = run;
#pragma unroll
        for (int cp = 0; cp < 8; cp++) {
            rbase[(size_t)cp * N_NODES + i] = run;
            run += cnts[cp];
        }
    }
}

// atomic-free CSR fill: slot = rbase[copy][dst] + within-copy ordinal
// (copy unpacked from ord bits [28..30], written by k_cnt)
__global__ void k_fill(const int* __restrict__ src, const int* __restrict__ dst,
                       const float* __restrict__ w, const float* __restrict__ dinv,
                       const int* __restrict__ rbase, const int* __restrict__ ord,
                       int2* __restrict__ csr) {
    int i = blockIdx.x * blockDim.x + threadIdx.x;
    if (i >= N_EDGES) return;
    int oc = ord[i];
    int copy = (oc >> 28) & 7;
    int o = oc & ((1 << 28) - 1);
    int s = src[i], d = dst[i];
    float nm = dinv[s] * w[i] * dinv[d];
    csr[rbase[(size_t)copy * N_NODES + d] + o] = make_int2(s, __float_as_int(nm));
}

// ---------------- layer 0 dense transform: [N,15]@[15,64] -> fp16 (no relu) ----

__global__ void k_gemm0(const float* __restrict__ x, const float* __restrict__ W,
                        __half* __restrict__ out) {
    __shared__ float Ws[F_IN * 64];
    int t = threadIdx.x;
    for (int i = t; i < F_IN * 64; i += 256) Ws[i] = W[i];
    __syncthreads();
    int r = blockIdx.x * 4 + (t >> 6);
    int c = t & 63;
    if (r < N_NODES) {
        const float* xr = x + (long)r * F_IN;
        float acc = 0.f;
#pragma unroll
        for (int k = 0; k < F_IN; k++) acc += xr[k] * Ws[k * 64 + c];
        out[(long)r * 64 + c] = __float2half(acc);
    }
}

// ---------------- fused aggregation + MFMA dense epilogue ----------------
// Inputs hin are stored POST-activation (relu applied by the producer), so the
// hot loop has no fmax. Wave = 8 nodes; lane = (sub: which edge of a pair) x
// (fl: feature pair). Records staged in LDS (no global->global chain); one
// global_load_dword covers 2 edges. acc is float2/lane, halves combined by
// one shfl_xor(32) pair per node.

#define SE_CAP 256          // staged edges per wave (chunked if exceeded)
#define G_STRIDE 72         // halves; 144 B rows keep half8 loads 16B-aligned

template <bool WEP, bool SIG>
__global__ __launch_bounds__(256) void k_gather4(
        const int* __restrict__ rowptr, const int2* __restrict__ csr,
        const __half* __restrict__ hin, const float* __restrict__ dinv,
        const float* __restrict__ W, const float* __restrict__ b,
        void* __restrict__ outp) {
    extern __shared__ char smem[];
    int t = threadIdx.x, wv = t >> 6, lane = t & 63;
    int sub = lane >> 5, fl = lane & 31;
    int2* se = (int2*)smem + wv * SE_CAP;                 // 4 x 2 KB
    _Float16* G = (_Float16*)(smem + 4 * SE_CAP * 8);     // [32][G_STRIDE]

    int nb = blockIdx.x * 32;      // grid exact: 3125*32 = 100000
    int n0w = nb + wv * 8;

    int rp[9];
#pragma unroll
    for (int j = 0; j < 9; j++) rp[j] = rowptr[n0w + j];
    int base = rp[0], end = rp[8];

    const __half2* h2 = (const __half2*)hin;  // row stride = 32 half2

    // self-loop init: acc[j] = dinv^2 * h (h already activated by producer)
    float2 acc[8];
#pragma unroll
    for (int j = 0; j < 8; j++) {
        int n = n0w + j;
        float dv = dinv[n];
        float2 hf = __half22float2(h2[(long)n * 32 + fl]);
        float w0 = (sub == 0) ? dv * dv : 0.f;
        acc[j].x = w0 * hf.x;
        acc[j].y = w0 * hf.y;
    }

    for (int cb = base; cb < end; cb += SE_CAP) {
        int ce = cb + SE_CAP; if (ce > end) ce = end;
        int cn = ce - cb;
        for (int i = lane; i < cn; i += 64) se[i] = csr[cb + i];
        __builtin_amdgcn_wave_barrier();
#pragma unroll
        for (int j = 0; j < 8; j++) {
            int lo = rp[j] < cb ? cb : rp[j];
            int hi = rp[j + 1] > ce ? ce : rp[j + 1];
            int i = lo - cb, iend = hi - cb;
            // 4 pairs (8 edges) per iteration
            for (; i + 7 < iend; i += 8) {
                int2 r0 = se[i + sub],     r1 = se[i + 2 + sub];
                int2 r2 = se[i + 4 + sub], r3 = se[i + 6 + sub];
                float2 f0 = __half22float2(h2[(long)r0.x * 32 + fl]);
                float2 f1 = __half22float2(h2[(long)r1.x * 32 + fl]);
                float2 f2 = __half22float2(h2[(long)r2.x * 32 + fl]);
                float2 f3 = __half22float2(h2[(long)r3.x * 32 + fl]);
                float n0 = __int_as_float(r0.y), n1 = __int_as_float(r1.y);
                float n2 = __int_as_float(r2.y), n3 = __int_as_float(r3.y);
                acc[j].x += n0 * f0.x; acc[j].y += n0 * f0.y;
                acc[j].x += n1 * f1.x; acc[j].y += n1 * f1.y;
                acc[j].x += n2 * f2.x; acc[j].y += n2 * f2.y;
                acc[j].x += n3 * f3.x; acc[j].y += n3 * f3.y;
            }
            for (; i + 1 < iend; i += 2) {
                int2 r = se[i + sub];
                float2 f = __half22float2(h2[(long)r.x * 32 + fl]);
                float nm = __int_as_float(r.y);
                acc[j].x += nm * f.x; acc[j].y += nm * f.y;
            }
            if (i < iend) {  // odd tail: sub0 only
                int2 r = se[i];
                float2 f = __half22float2(h2[(long)r.x * 32 + fl]);
                float nm = (sub == 0) ? __int_as_float(r.y) : 0.f;
                acc[j].x += nm * f.x; acc[j].y += nm * f.y;
            }
        }
        __builtin_amdgcn_wave_barrier();
    }

    // combine sub-halves: feature pair fl lives in lanes fl and fl+32
#pragma unroll
    for (int j = 0; j < 8; j++) {
        acc[j].x += __shfl_xor(acc[j].x, 32);
        acc[j].y += __shfl_xor(acc[j].y, 32);
    }

    if (!WEP) {
        // layer 0: out = relu(g + b) fp16, written as half2 by sub0 lanes
        float2 bv = ((const float2*)b)[fl];
        if (sub == 0) {
#pragma unroll
            for (int j = 0; j < 8; j++) {
                float ox = fmaxf(acc[j].x + bv.x, 0.f);
                float oy = fmaxf(acc[j].y + bv.y, 0.f);
                ((__half2*)outp)[(long)(n0w + j) * 32 + fl] = __floats2half2_rn(ox, oy);
            }
        }
        return;
    }

    // write G rows (fp16) from sub0 lanes
    if (sub == 0) {
        __half2* G2 = (__half2*)G;
#pragma unroll
        for (int j = 0; j < 8; j++)
            G2[(wv * 8 + j) * (G_STRIDE / 2) + fl] = __floats2half2_rn(acc[j].x, acc[j].y);
    }
    __syncthreads();

    // ---- MFMA epilogue: O[32x64] = G @ (W_hi + W_lo) + b ----
    int col = lane & 15, quad = lane >> 4;
    int mrow = (wv & 1) * 16;
    int nc0 = (wv >> 1) * 32;

    half8 af[2];
#pragma unroll
    for (int kt = 0; kt < 2; kt++)
        af[kt] = *(const half8*)&G[(mrow + col) * G_STRIDE + kt * 32 + quad * 8];

    half8 bf[2][2][2];  // [nt][kt][hi/lo]
#pragma unroll
    for (int nt = 0; nt < 2; nt++) {
#pragma unroll
        for (int kt = 0; kt < 2; kt++) {
#pragma unroll
            for (int j = 0; j < 8; j++) {
                float w = W[(kt * 32 + quad * 8 + j) * 64 + nc0 + nt * 16 + col];
                _Float16 hi = (_Float16)w;
                bf[nt][kt][0][j] = hi;
                bf[nt][kt][1][j] = (_Float16)(w - (float)hi);
            }
        }
    }

    f32x4 c0, c1;
    {
        float b0v = b[nc0 + col], b1v = b[nc0 + 16 + col];
        c0 = (f32x4){b0v, b0v, b0v, b0v};
        c1 = (f32x4){b1v, b1v, b1v, b1v};
    }
#pragma unroll
    for (int kt = 0; kt < 2; kt++) {
        c0 = __builtin_amdgcn_mfma_f32_16x16x32_f16(af[kt], bf[0][kt][0], c0, 0, 0, 0);
        c0 = __builtin_amdgcn_mfma_f32_16x16x32_f16(af[kt], bf[0][kt][1], c0, 0, 0, 0);
        c1 = __builtin_amdgcn_mfma_f32_16x16x32_f16(af[kt], bf[1][kt][0], c1, 0, 0, 0);
        c1 = __builtin_amdgcn_mfma_f32_16x16x32_f16(af[kt], bf[1][kt][1], c1, 0, 0, 0);
    }

    // C/D: col = lane&15, row = quad*4 + reg
#pragma unroll
    for (int nt = 0; nt < 2; nt++) {
        f32x4 c = nt ? c1 : c0;
#pragma unroll
        for (int r = 0; r < 4; r++) {
            long node = nb + mrow + quad * 4 + r;
            int feat = nc0 + nt * 16 + col;
            float o = c[r];
            if (SIG) {
                o = 1.0f / (1.0f + expf(-o));
                ((float*)outp)[node * 64 + feat] = o;
            } else {
                o = fmaxf(o, 0.f);  // relu at producer: store post-activation
                ((__half*)outp)[node * 64 + feat] = __float2half(o);
            }
        }
    }
}

// ---------------- launch ----------------

extern "C" void kernel_launch(void* const* d_in, const int* in_sizes, int n_in,
                              void* d_out, int out_size, void* d_ws, size_t ws_size,
                              hipStream_t stream) {
    const float* x  = (const float*)d_in[0];
    const int*   ei = (const int*)  d_in[1];
    const float* ew = (const float*)d_in[2];
    const float* W0 = (const float*)d_in[3];
    const float* b0 = (const float*)d_in[4];
    const float* Wm = (const float*)d_in[5];
    const float* bm = (const float*)d_in[6];
    const float* Wl = (const float*)d_in[7];
    const float* bl = (const float*)d_in[8];
    float* out = (float*)d_out;

    const int* src = ei;
    const int* dst = ei + N_EDGES;

    char* ws = (char*)d_ws;
    unsigned long long* packed8 = (unsigned long long*)(ws + 0);       // 6.4 MB
    float*  dinv   = (float*)(ws + (7u  << 20));                        // 400 KB
    int*    rowptr = (int*)  (ws + (8u  << 20));                        // 400 KB
    int*    bsum   = (int*)  (ws + (9u  << 20));                        // 2 KB
    int*    ord    = (int*)  (ws + (9u  << 20) + 65536);                // 6.4 MB
    int*    rbase  = (int*)  (ws + (16u << 20));                        // 3.2 MB
    int2*   csr    = (int2*) (ws + (20u << 20));                        // 12.8 MB
    __half* htmp   = (__half*)(ws + (33u << 20));                       // 12.8 MB
    __half* hA     = (__half*)(ws + (46u << 20));                       // 12.8 MB
    __half* hB     = (__half*)(ws + (59u << 20));                       // 12.8 MB

    const int BT = 256;
    dim3 blk(BT);
    int gN  = NB_NODES;                       // 391
    int gN8 = (8 * N_NODES + BT - 1) / BT;    // 3125 (init packed8)
    int gE  = (N_EDGES + BT - 1) / BT;        // 6250
    int gR4 = (N_NODES + 3) / 4;              // 25000 (gemm0)
    int gG  = N_NODES / 32;                   // 3125 (gather4: 32 nodes/block)

    const size_t smem0 = 4 * SE_CAP * 8;                          // 8 KB
    const size_t smemW = 4 * SE_CAP * 8 + 32 * G_STRIDE * 2;      // 12.5 KB

    // prelude: 8-way replicated count+degree, 3-phase scan, atomic-free CSR fill
    hipLaunchKernelGGL(k_initp,   dim3(gN8), blk, 0, stream, packed8);
    hipLaunchKernelGGL(k_cnt,     dim3(gE),  blk, 0, stream, dst, ew, packed8, ord);
    hipLaunchKernelGGL(k_part,    dim3(gN),  blk, 0, stream, packed8, bsum, dinv);
    hipLaunchKernelGGL(k_scanb,   dim3(1), dim3(512), 0, stream, bsum, rowptr);
    hipLaunchKernelGGL(k_fillptr, dim3(gN),  blk, 0, stream, packed8, bsum, rowptr, rbase);
    hipLaunchKernelGGL(k_fill,    dim3(gE),  blk, 0, stream, src, dst, ew, dinv, rbase, ord, csr);

    // layer 0: x W0 -> fp16 (pre-act), then aggregate +b0, relu at store -> hA
    hipLaunchKernelGGL(k_gemm0,   dim3(gR4), blk, 0, stream, x, W0, htmp);
    hipLaunchKernelGGL((k_gather4<false, false>), dim3(gG), blk, smem0, stream,
                       rowptr, csr, htmp, dinv, (const float*)nullptr, b0, (void*)hA);

    // middle layers 1..6: fused (A h) W + b via MFMA, relu at store, fp16 -> fp16
    __half* hin = hA;
    __half* hout = hB;
    for (int i = 0; i < 6; i++) {
        const float* Wi = Wm + (long)i * 64 * 64;
        const float* bi = bm + (long)i * 64;
        hipLaunchKernelGGL((k_gather4<true, false>), dim3(gG), blk, smemW, stream,
                           rowptr, csr, hin, dinv, Wi, bi, (void*)hout);
        __half* t2 = hin; hin = hout; hout = t2;
    }

    // final layer: fused aggregate + W + bias + sigmoid -> fp32 d_out
    hipLaunchKernelGGL((k_gather4<true, true>), dim3(gG), blk, smemW, stream,
                       rowptr, csr, hin, dinv, Wl, bl, (void*)out);
}

// Round 2
// 505.587 us; speedup vs baseline: 1.1331x; 1.1331x over previous
//
#include <hip/hip_runtime.h>
#include <hip/hip_fp16.h>
#include <math.h>

#define N_NODES 100000
#define N_EDGES 1600000
#define F_IN 15
#define MASK40 ((1ull << 40) - 1)

// bucketed counting-sort CSR build: buckets of 512 nodes (dst>>9)
#define NBLK1 256                           // edge-partition blocks for hist/scatter
#define EPB   (N_EDGES / NBLK1)             // 6250 edges per block (exact)
#define NBUCK 256                           // allocated buckets; used = 196
#define NBUCK_USED ((N_NODES + 511) >> 9)   // 196

typedef _Float16 half8 __attribute__((ext_vector_type(8)));
typedef float f32x4 __attribute__((ext_vector_type(4)));

// ---------------- prelude: sort-based CSR build (no global atomics) ----------

// per-block 256-bin histogram of dst>>9 in LDS; hist[bin*NBLK1 + blk]
__global__ __launch_bounds__(1024) void k_hist(const int* __restrict__ dst,
                                               int* __restrict__ hist) {
    __shared__ int bins[NBUCK];
    int t = threadIdx.x, blk = blockIdx.x;
    if (t < NBUCK) bins[t] = 0;
    __syncthreads();
    int e0 = blk * EPB;
    for (int e = e0 + t; e < e0 + EPB; e += 1024)
        atomicAdd(&bins[dst[e] >> 9], 1);
    __syncthreads();
    if (t < NBUCK) hist[t * NBLK1 + blk] = bins[t];
}

// single-block exclusive scan of hist[65536] in place; also bucketBase[b] =
// scan value at b*NBLK1, bucketBase[NBUCK]=E, rowptr[N]=E.
__global__ __launch_bounds__(1024) void k_scan(int* __restrict__ hist,
                                               int* __restrict__ bucketBase,
                                               int* __restrict__ rowptr) {
    __shared__ int sc[1024];
    int t = threadIdx.x;
    int base = t * 64;
    int vals[64];
    int tot = 0;
#pragma unroll
    for (int k = 0; k < 64; k++) { vals[k] = hist[base + k]; tot += vals[k]; }
    sc[t] = tot;
    __syncthreads();
    for (int off = 1; off < 1024; off <<= 1) {
        int u = (t >= off) ? sc[t - off] : 0;
        __syncthreads();
        sc[t] += u;
        __syncthreads();
    }
    int run = sc[t] - tot;  // exclusive base of this thread's segment
#pragma unroll
    for (int k = 0; k < 64; k++) {
        int idx = base + k;
        if ((idx & (NBLK1 - 1)) == 0) bucketBase[idx / NBLK1] = run;
        int v = vals[k];
        hist[idx] = run;
        run += v;
    }
    if (t == 0) { bucketBase[NBUCK] = N_EDGES; rowptr[N_NODES] = N_EDGES; }
}

// scatter edges into bucket-contiguous record array via LDS cursors.
// record: x = src | (dst&511)<<17  (src<2^17, 9-bit dstlo), y = bits(w)
__global__ __launch_bounds__(1024) void k_scatter(const int* __restrict__ src,
        const int* __restrict__ dst, const float* __restrict__ w,
        const int* __restrict__ hist, int2* __restrict__ brec) {
    __shared__ int cursor[NBUCK];
    int t = threadIdx.x, blk = blockIdx.x;
    if (t < NBUCK) cursor[t] = hist[t * NBLK1 + blk];
    __syncthreads();
    int e0 = blk * EPB;
    for (int e = e0 + t; e < e0 + EPB; e += 1024) {
        int d = dst[e];
        int pos = atomicAdd(&cursor[d >> 9], 1);
        brec[pos] = make_int2(src[e] | ((d & 511) << 17), __float_as_int(w[e]));
    }
}

// per-bucket: packed count/weight-sum per node in LDS (same 24.40 packing as
// the old k_cnt -> identical deg numerics), then dinv + rowptr via LDS scan.
__global__ __launch_bounds__(512) void k_deg(const int2* __restrict__ brec,
        const int* __restrict__ bucketBase, float* __restrict__ dinv,
        int* __restrict__ rowptr) {
    __shared__ unsigned long long packedl[512];
    __shared__ int sc[512];
    int t = threadIdx.x, b = blockIdx.x;
    packedl[t] = 0ull;
    __syncthreads();
    int ebase = bucketBase[b], eend = bucketBase[b + 1];
    for (int e = ebase + t; e < eend; e += 512) {
        int2 r = brec[e];
        int dlo = (r.x >> 17) & 511;
        float wv = __int_as_float(r.y);
        unsigned long long contrib =
            (1ull << 40) + (unsigned long long)((double)wv * 4294967296.0);
        atomicAdd(&packedl[dlo], contrib);
    }
    __syncthreads();
    unsigned long long p = packedl[t];
    int cnt = (int)(p >> 40);
    int n = (b << 9) + t;
    if (n < N_NODES) {
        float deg = 1.0f + (float)((double)(p & MASK40) * 0x1p-32);
        dinv[n] = rsqrtf(deg);
    }
    sc[t] = cnt;
    __syncthreads();
    for (int off = 1; off < 512; off <<= 1) {
        int u = (t >= off) ? sc[t - off] : 0;
        __syncthreads();
        sc[t] += u;
        __syncthreads();
    }
    if (n < N_NODES) rowptr[n] = ebase + sc[t] - cnt;  // exclusive prefix
}

// per-bucket final CSR fill: LDS cursors seeded from rowptr; nm in fp32 with
// the exact formula the old k_fill used.
__global__ __launch_bounds__(512) void k_csr(const int2* __restrict__ brec,
        const int* __restrict__ bucketBase, const int* __restrict__ rowptr,
        const float* __restrict__ dinv, int2* __restrict__ csr) {
    __shared__ int cursor[512];
    __shared__ float dl[512];
    int t = threadIdx.x, b = blockIdx.x;
    int n = (b << 9) + t;
    if (n < N_NODES) { cursor[t] = rowptr[n]; dl[t] = dinv[n]; }
    else             { cursor[t] = 0;         dl[t] = 0.f; }
    __syncthreads();
    int ebase = bucketBase[b], eend = bucketBase[b + 1];
    for (int e = ebase + t; e < eend; e += 512) {
        int2 r = brec[e];
        int dlo = (r.x >> 17) & 511;
        int s = r.x & 0x1FFFF;
        float wv = __int_as_float(r.y);
        int slot = atomicAdd(&cursor[dlo], 1);
        float nm = dinv[s] * wv * dl[dlo];
        csr[slot] = make_int2(s, __float_as_int(nm));
    }
}

// ---------------- layer 0 dense transform: [N,15]@[15,64] -> fp16 (no relu) ----

__global__ void k_gemm0(const float* __restrict__ x, const float* __restrict__ W,
                        __half* __restrict__ out) {
    __shared__ float Ws[F_IN * 64];
    int t = threadIdx.x;
    for (int i = t; i < F_IN * 64; i += 256) Ws[i] = W[i];
    __syncthreads();
    int r = blockIdx.x * 4 + (t >> 6);
    int c = t & 63;
    if (r < N_NODES) {
        const float* xr = x + (long)r * F_IN;
        float acc = 0.f;
#pragma unroll
        for (int k = 0; k < F_IN; k++) acc += xr[k] * Ws[k * 64 + c];
        out[(long)r * 64 + c] = __float2half(acc);
    }
}

// ---------------- fused aggregation + MFMA dense epilogue ----------------
// Inputs hin are stored POST-activation (relu applied by the producer), so the
// hot loop has no fmax. Wave = 8 nodes; lane = (sub: which edge of a pair) x
// (fl: feature pair). Records staged in LDS (no global->global chain); one
// global_load_dword covers 2 edges. acc is float2/lane, halves combined by
// one shfl_xor(32) pair per node.

#define SE_CAP 256          // staged edges per wave (chunked if exceeded)
#define G_STRIDE 72         // halves; 144 B rows keep half8 loads 16B-aligned

template <bool WEP, bool SIG>
__global__ __launch_bounds__(256) void k_gather4(
        const int* __restrict__ rowptr, const int2* __restrict__ csr,
        const __half* __restrict__ hin, const float* __restrict__ dinv,
        const float* __restrict__ W, const float* __restrict__ b,
        void* __restrict__ outp) {
    extern __shared__ char smem[];
    int t = threadIdx.x, wv = t >> 6, lane = t & 63;
    int sub = lane >> 5, fl = lane & 31;
    int2* se = (int2*)smem + wv * SE_CAP;                 // 4 x 2 KB
    _Float16* G = (_Float16*)(smem + 4 * SE_CAP * 8);     // [32][G_STRIDE]

    int nb = blockIdx.x * 32;      // grid exact: 3125*32 = 100000
    int n0w = nb + wv * 8;

    int rp[9];
#pragma unroll
    for (int j = 0; j < 9; j++) rp[j] = rowptr[n0w + j];
    int base = rp[0], end = rp[8];

    const __half2* h2 = (const __half2*)hin;  // row stride = 32 half2

    // self-loop init: acc[j] = dinv^2 * h (h already activated by producer)
    float2 acc[8];
#pragma unroll
    for (int j = 0; j < 8; j++) {
        int n = n0w + j;
        float dv = dinv[n];
        float2 hf = __half22float2(h2[(long)n * 32 + fl]);
        float w0 = (sub == 0) ? dv * dv : 0.f;
        acc[j].x = w0 * hf.x;
        acc[j].y = w0 * hf.y;
    }

    for (int cb = base; cb < end; cb += SE_CAP) {
        int ce = cb + SE_CAP; if (ce > end) ce = end;
        int cn = ce - cb;
        for (int i = lane; i < cn; i += 64) se[i] = csr[cb + i];
        __builtin_amdgcn_wave_barrier();
#pragma unroll
        for (int j = 0; j < 8; j++) {
            int lo = rp[j] < cb ? cb : rp[j];
            int hi = rp[j + 1] > ce ? ce : rp[j + 1];
            int i = lo - cb, iend = hi - cb;
            // 4 pairs (8 edges) per iteration
            for (; i + 7 < iend; i += 8) {
                int2 r0 = se[i + sub],     r1 = se[i + 2 + sub];
                int2 r2 = se[i + 4 + sub], r3 = se[i + 6 + sub];
                float2 f0 = __half22float2(h2[(long)r0.x * 32 + fl]);
                float2 f1 = __half22float2(h2[(long)r1.x * 32 + fl]);
                float2 f2 = __half22float2(h2[(long)r2.x * 32 + fl]);
                float2 f3 = __half22float2(h2[(long)r3.x * 32 + fl]);
                float n0 = __int_as_float(r0.y), n1 = __int_as_float(r1.y);
                float n2 = __int_as_float(r2.y), n3 = __int_as_float(r3.y);
                acc[j].x += n0 * f0.x; acc[j].y += n0 * f0.y;
                acc[j].x += n1 * f1.x; acc[j].y += n1 * f1.y;
                acc[j].x += n2 * f2.x; acc[j].y += n2 * f2.y;
                acc[j].x += n3 * f3.x; acc[j].y += n3 * f3.y;
            }
            for (; i + 1 < iend; i += 2) {
                int2 r = se[i + sub];
                float2 f = __half22float2(h2[(long)r.x * 32 + fl]);
                float nm = __int_as_float(r.y);
                acc[j].x += nm * f.x; acc[j].y += nm * f.y;
            }
            if (i < iend) {  // odd tail: sub0 only
                int2 r = se[i];
                float2 f = __half22float2(h2[(long)r.x * 32 + fl]);
                float nm = (sub == 0) ? __int_as_float(r.y) : 0.f;
                acc[j].x += nm * f.x; acc[j].y += nm * f.y;
            }
        }
        __builtin_amdgcn_wave_barrier();
    }

    // combine sub-halves: feature pair fl lives in lanes fl and fl+32
#pragma unroll
    for (int j = 0; j < 8; j++) {
        acc[j].x += __shfl_xor(acc[j].x, 32);
        acc[j].y += __shfl_xor(acc[j].y, 32);
    }

    if (!WEP) {
        // layer 0: out = relu(g + b) fp16, written as half2 by sub0 lanes
        float2 bv = ((const float2*)b)[fl];
        if (sub == 0) {
#pragma unroll
            for (int j = 0; j < 8; j++) {
                float ox = fmaxf(acc[j].x + bv.x, 0.f);
                float oy = fmaxf(acc[j].y + bv.y, 0.f);
                ((__half2*)outp)[(long)(n0w + j) * 32 + fl] = __floats2half2_rn(ox, oy);
            }
        }
        return;
    }

    // write G rows (fp16) from sub0 lanes
    if (sub == 0) {
        __half2* G2 = (__half2*)G;
#pragma unroll
        for (int j = 0; j < 8; j++)
            G2[(wv * 8 + j) * (G_STRIDE / 2) + fl] = __floats2half2_rn(acc[j].x, acc[j].y);
    }
    __syncthreads();

    // ---- MFMA epilogue: O[32x64] = G @ (W_hi + W_lo) + b ----
    int col = lane & 15, quad = lane >> 4;
    int mrow = (wv & 1) * 16;
    int nc0 = (wv >> 1) * 32;

    half8 af[2];
#pragma unroll
    for (int kt = 0; kt < 2; kt++)
        af[kt] = *(const half8*)&G[(mrow + col) * G_STRIDE + kt * 32 + quad * 8];

    half8 bf[2][2][2];  // [nt][kt][hi/lo]
#pragma unroll
    for (int nt = 0; nt < 2; nt++) {
#pragma unroll
        for (int kt = 0; kt < 2; kt++) {
#pragma unroll
            for (int j = 0; j < 8; j++) {
                float w = W[(kt * 32 + quad * 8 + j) * 64 + nc0 + nt * 16 + col];
                _Float16 hi = (_Float16)w;
                bf[nt][kt][0][j] = hi;
                bf[nt][kt][1][j] = (_Float16)(w - (float)hi);
            }
        }
    }

    f32x4 c0, c1;
    {
        float b0v = b[nc0 + col], b1v = b[nc0 + 16 + col];
        c0 = (f32x4){b0v, b0v, b0v, b0v};
        c1 = (f32x4){b1v, b1v, b1v, b1v};
    }
#pragma unroll
    for (int kt = 0; kt < 2; kt++) {
        c0 = __builtin_amdgcn_mfma_f32_16x16x32_f16(af[kt], bf[0][kt][0], c0, 0, 0, 0);
        c0 = __builtin_amdgcn_mfma_f32_16x16x32_f16(af[kt], bf[0][kt][1], c0, 0, 0, 0);
        c1 = __builtin_amdgcn_mfma_f32_16x16x32_f16(af[kt], bf[1][kt][0], c1, 0, 0, 0);
        c1 = __builtin_amdgcn_mfma_f32_16x16x32_f16(af[kt], bf[1][kt][1], c1, 0, 0, 0);
    }

    // C/D: col = lane&15, row = quad*4 + reg
#pragma unroll
    for (int nt = 0; nt < 2; nt++) {
        f32x4 c = nt ? c1 : c0;
#pragma unroll
        for (int r = 0; r < 4; r++) {
            long node = nb + mrow + quad * 4 + r;
            int feat = nc0 + nt * 16 + col;
            float o = c[r];
            if (SIG) {
                o = 1.0f / (1.0f + expf(-o));
                ((float*)outp)[node * 64 + feat] = o;
            } else {
                o = fmaxf(o, 0.f);  // relu at producer: store post-activation
                ((__half*)outp)[node * 64 + feat] = __float2half(o);
            }
        }
    }
}

// ---------------- launch ----------------

extern "C" void kernel_launch(void* const* d_in, const int* in_sizes, int n_in,
                              void* d_out, int out_size, void* d_ws, size_t ws_size,
                              hipStream_t stream) {
    const float* x  = (const float*)d_in[0];
    const int*   ei = (const int*)  d_in[1];
    const float* ew = (const float*)d_in[2];
    const float* W0 = (const float*)d_in[3];
    const float* b0 = (const float*)d_in[4];
    const float* Wm = (const float*)d_in[5];
    const float* bm = (const float*)d_in[6];
    const float* Wl = (const float*)d_in[7];
    const float* bl = (const float*)d_in[8];
    float* out = (float*)d_out;

    const int* src = ei;
    const int* dst = ei + N_EDGES;

    char* ws = (char*)d_ws;
    int*    hist   = (int*)  (ws + 0);                // 256 KB (NBUCK*NBLK1*4)
    int*    bbase  = (int*)  (ws + (1u << 18));       // ~1 KB (NBUCK+1 ints)
    float*  dinv   = (float*)(ws + (1u << 20));       // 400 KB
    int*    rowptr = (int*)  (ws + (2u << 20));       // 400 KB + 4
    int2*   brec   = (int2*) (ws + (3u << 20));       // 12.8 MB
    int2*   csr    = (int2*) (ws + (16u << 20));      // 12.8 MB
    __half* htmp   = (__half*)(ws + (29u << 20));     // 12.8 MB
    __half* hA     = (__half*)(ws + (42u << 20));     // 12.8 MB
    __half* hB     = (__half*)(ws + (55u << 20));     // 12.8 MB

    int gR4 = (N_NODES + 3) / 4;              // 25000 (gemm0)
    int gG  = N_NODES / 32;                   // 3125 (gather4: 32 nodes/block)

    const size_t smem0 = 4 * SE_CAP * 8;                          // 8 KB
    const size_t smemW = 4 * SE_CAP * 8 + 32 * G_STRIDE * 2;      // 12.5 KB

    // prelude: bucketed counting sort (LDS atomics only), then per-bucket
    // degree/rowptr and final CSR fill
    hipLaunchKernelGGL(k_hist,    dim3(NBLK1), dim3(1024), 0, stream, dst, hist);
    hipLaunchKernelGGL(k_scan,    dim3(1),     dim3(1024), 0, stream, hist, bbase, rowptr);
    hipLaunchKernelGGL(k_scatter, dim3(NBLK1), dim3(1024), 0, stream, src, dst, ew, hist, brec);
    hipLaunchKernelGGL(k_deg,     dim3(NBUCK_USED), dim3(512), 0, stream, brec, bbase, dinv, rowptr);
    hipLaunchKernelGGL(k_csr,     dim3(NBUCK_USED), dim3(512), 0, stream, brec, bbase, rowptr, dinv, csr);

    // layer 0: x W0 -> fp16 (pre-act), then aggregate +b0, relu at store -> hA
    hipLaunchKernelGGL(k_gemm0,   dim3(gR4), dim3(256), 0, stream, x, W0, htmp);
    hipLaunchKernelGGL((k_gather4<false, false>), dim3(gG), dim3(256), smem0, stream,
                       rowptr, csr, htmp, dinv, (const float*)nullptr, b0, (void*)hA);

    // middle layers 1..6: fused (A h) W + b via MFMA, relu at store, fp16 -> fp16
    __half* hin = hA;
    __half* hout = hB;
    for (int i = 0; i < 6; i++) {
        const float* Wi = Wm + (long)i * 64 * 64;
        const float* bi = bm + (long)i * 64;
        hipLaunchKernelGGL((k_gather4<true, false>), dim3(gG), dim3(256), smemW, stream,
                           rowptr, csr, hin, dinv, Wi, bi, (void*)hout);
        __half* t2 = hin; hin = hout; hout = t2;
    }

    // final layer: fused aggregate + W + bias + sigmoid -> fp32 d_out
    hipLaunchKernelGGL((k_gather4<true, true>), dim3(gG), dim3(256), smemW, stream,
                       rowptr, csr, hin, dinv, Wl, bl, (void*)out);
}